// Round 15
// baseline (303.216 us; speedup 1.0000x reference)
//
#include <hip/hip_runtime.h>

#define DD   121
#define NHID 15
#define NBLK 5
#define KS   11
#define IW   4096
#define OW   2043

// DPP row-rotate add: v += rotate_within_16_lane_row(v, N). VALU-only reduce.
#define ROR_ADD(v, N)                                                         \
  v += __int_as_float(__builtin_amdgcn_update_dpp(                            \
      0, __float_as_int(v), 0x120 + (N), 0xF, 0xF, true))

// Packed staging: W1 direct; W2 as per-idx (m,a) pairs; b2 as (m,a) pairs.
__device__ __forceinline__ void stage_weights(
    float* W1d, float* W2d, float* b2d, float* b1d,
    const float* __restrict__ W1, const float* __restrict__ W2,
    const float* __restrict__ b2, const float* __restrict__ b1,
    int blk, int t0, int nt)
{
    const float* W1b = W1 + blk * NHID * DD;
    const float* W2b = W2 + blk * 2 * DD * NHID;
    const float* b2b = b2 + blk * 2 * DD;
    for (int i = t0; i < NHID * DD; i += nt) W1d[i] = W1b[i];   // [j*DD+idx]
    for (int k = t0; k < DD * NHID; k += nt) {
        const int idx = k / NHID, j = k - idx * NHID;
        W2d[idx*32 + 2*j]     = W2b[idx*NHID + j];         // m-weight
        W2d[idx*32 + 2*j + 1] = W2b[(DD + idx)*NHID + j];  // loga-weight
    }
    for (int i = t0; i < DD; i += nt) {
        W2d[i*32 + 30] = 0.f;                              // pad lane 15
        W2d[i*32 + 31] = 0.f;
        b2d[2*i]     = b2b[i];
        b2d[2*i + 1] = b2b[DD + i];
    }
    for (int i = t0; i < NHID; i += nt) b1d[i] = b1[blk*NHID + i];
}

// ---------------------------------------------------------------------------
// Flow inverse (MAF) + post-process. 2 waves: wave0 scans (lanes 0..15, DPP
// reduce, 4-slot named-register prefetch distance 4), wave1 stages next
// block's weights into the other LDS buffer. (unchanged from r11-r13)
// ---------------------------------------------------------------------------
__global__ __launch_bounds__(128) void flow_kernel(
    const float* __restrict__ kc,
    const float* __restrict__ W1, const float* __restrict__ b1,
    const float* __restrict__ W2, const float* __restrict__ b2,
    const float* __restrict__ lg, const float* __restrict__ beta,
    const float* __restrict__ mean, const float* __restrict__ var,
    float* __restrict__ kout)
{
    __shared__ float xs[DD];
    __shared__ float us[DD];
    __shared__ float W1s[2][NHID * DD];
    __shared__ float W2p[2][DD * 32];     // [idx*32 + 2j] = (m, a) pair
    __shared__ float b2p[2][DD * 2];      // [2*idx] = (m, a) pair
    __shared__ float b1s[2][16];

    const int tid  = threadIdx.x;
    const int wv   = tid >> 6;
    const int lane = tid & 63;

    stage_weights(W1s[0], W2p[0], b2p[0], b1s[0], W1, W2, b2, b1, NBLK - 1, tid, 128);
    if (tid < DD) xs[tid] = kc[tid];
    __syncthreads();

    for (int b = NBLK - 1; b >= 0; --b) {
        const int buf = (NBLK - 1 - b) & 1;
        if (wv == 1) {
            if (b > 0)
                stage_weights(W1s[buf^1], W2p[buf^1], b2p[buf^1], b1s[buf^1],
                              W1, W2, b2, b1, b - 1, lane, 64);
        } else {
            // BatchNorm inverse (eval): x = (x-beta)*exp(-lg)*sqrt(var+eps)+mean
            for (int i = lane; i < DD; i += 64) {
                float s = sqrtf(var[b*DD + i] + 1e-5f);
                us[i] = (xs[i] - beta[b*DD + i]) * __expf(-lg[b*DD + i]) * s + mean[b*DD + i];
            }
            const int evenb = ((b & 1) == 0);
            if (lane < 16) {
                const int j  = lane;
                const int jc = (j < NHID) ? j : (NHID - 1);   // clamp W1 row addr
                float pre_h = (j < NHID) ? b1s[buf][j] : 0.f;

                auto step = [&](int t, int iS, float2 wpS, float w1S, float uvS, float2 bpS) {
                    float h  = (j < t && j < NHID) ? fmaxf(pre_h, 0.f) : 0.f;
                    float pm = h * wpS.x;
                    float pa = h * wpS.y;
                    ROR_ADD(pm, 1); ROR_ADD(pa, 1);
                    ROR_ADD(pm, 2); ROR_ADD(pa, 2);
                    ROR_ADD(pm, 4); ROR_ADD(pa, 4);
                    ROR_ADD(pm, 8); ROR_ADD(pa, 8);
                    const float xv = fmaf(uvS, __expf(pa + bpS.y), pm + bpS.x);
                    if (j >= t && j < NHID) pre_h = fmaf(xv, w1S, pre_h);
                    if (j == 0) xs[iS] = xv;
                };

                int iA, iB, iC, iD;
                float2 wpA, wpB, wpC, wpD, bpA, bpB, bpC, bpD;
                float  w1A, w1B, w1C, w1D, uvA, uvB, uvC, uvD;

                #define PRELOAD(S, T) { const int tt = (T);                                 \
                    i##S  = evenb ? tt : (DD - 1 - tt);                                     \
                    wp##S = *(const float2*)&W2p[buf][i##S*32 + 2*j];                       \
                    w1##S = W1s[buf][jc*DD + i##S];                                         \
                    uv##S = us[i##S];                                                       \
                    bp##S = *(const float2*)&b2p[buf][2*i##S]; }

                #define QSTEP(S, TCUR, TNEXT) {                                             \
                    int tt = (TNEXT); if (tt > DD - 1) tt = DD - 1;                         \
                    const int ip = evenb ? tt : (DD - 1 - tt);                              \
                    const float2 wpN = *(const float2*)&W2p[buf][ip*32 + 2*j];              \
                    const float  w1N = W1s[buf][jc*DD + ip];                                \
                    const float  uvN = us[ip];                                              \
                    const float2 bpN = *(const float2*)&b2p[buf][2*ip];                     \
                    step((TCUR), i##S, wp##S, w1##S, uv##S, bp##S);                         \
                    i##S = ip; wp##S = wpN; w1##S = w1N; uv##S = uvN; bp##S = bpN; }

                PRELOAD(A, 0) PRELOAD(B, 1) PRELOAD(C, 2) PRELOAD(D, 3)
                #pragma unroll 1
                for (int it = 0; it < 30; ++it) {        // t = 4it .. 4it+3; DD-1=120=4*30
                    QSTEP(A, 4*it + 0, 4*it + 4)
                    QSTEP(B, 4*it + 1, 4*it + 5)
                    QSTEP(C, 4*it + 2, 4*it + 6)
                    QSTEP(D, 4*it + 3, 4*it + 7)
                }
                step(DD - 1, iA, wpA, w1A, uvA, bpA);    // final step t=120
                #undef PRELOAD
                #undef QSTEP
            }
        }
        __syncthreads();
    }

    // post-process: y = (sigmoid(x)-a)/(1-2a); k = y/sum(y)
    if (tid < 64) {
        const float A = 1e-6f;
        float y0, y1 = 0.f;
        {
            float v = xs[tid];
            y0 = (1.f / (1.f + __expf(-v)) - A) / (1.f - 2.f*A);
        }
        if (tid + 64 < DD) {
            float v = xs[tid + 64];
            y1 = (1.f / (1.f + __expf(-v)) - A) / (1.f - 2.f*A);
        }
        float s = y0 + y1;
        #pragma unroll
        for (int off = 32; off >= 1; off >>= 1) s += __shfl_xor(s, off, 64);
        kout[tid] = y0 / s;
        if (tid + 64 < DD) kout[tid + 64] = y1 / s;
    }
}

// ---------------------------------------------------------------------------
// STREAMING SYSTOLIC 11x11 stride-2 conv. Single-wave blocks (64 threads).
// Lane l owns 4 output columns ox = ox0+4l..+3 (tile 256 wide) and streams
// down a 13-output-row strip. Ring of 6 register accumulators: input-row
// pair p (rows 2p,2p+1) contributes ky=2a / 2a+1 to live rows oy=p-a
// (a=0..5), completing oy=p-5 each pair -> 2.5 LDS b128 reads per output
// (vs 8.1-13.75 in the tiled versions; LDS-pipe pressure was the r11-r13
// wall). Ring indices static via 6-unroll (p = 6g+u). No barriers.
// Per-pair global loads (2 rows, coalesced) hidden under 484 FMA.
// ---------------------------------------------------------------------------
#define HSTRIP 13
#define NPAIRG 3              // 18 pairs = 3 groups x 6

__global__ __launch_bounds__(64) void conv_kernel(
    const float* __restrict__ in, const float* __restrict__ kf,
    float* __restrict__ out)
{
    __shared__ __align__(16) float Ee[2][264];   // even-x words of pair rows
    __shared__ __align__(16) float Oo[2][264];   // odd-x words

    const int l   = threadIdx.x;
    const int ox0 = blockIdx.x * 256;
    const int gx0 = ox0 * 2;
    const int oy0 = blockIdx.y * HSTRIP;
    const int gy0 = oy0 * 2;
    const int ch  = blockIdx.z;

    const float* __restrict__ inc  = in  + (size_t)ch * IW * IW;
    float*       __restrict__ outc = out + (size_t)ch * OW * OW;
    const int xlim = IW - gx0;            // valid words w < xlim (>= 512)

    float acc[6][4] = {};

    float4 g0a, g0b, g1a, g1b;
    float  g0t, g1t;

    auto gload = [&](int p) {
        const int ir0 = gy0 + 2*p;
        const float* r0 = inc + (size_t)ir0 * IW + gx0;
        const float* r1 = r0 + IW;
        const bool ok0 = (ir0     < IW);
        const bool ok1 = (ir0 + 1 < IW);
        g0a = make_float4(0.f,0.f,0.f,0.f); g0b = g0a; g1a = g0a; g1b = g0a;
        g0t = 0.f; g1t = 0.f;
        if (ok0) { g0a = *(const float4*)(r0 + 4*l); g0b = *(const float4*)(r0 + 256 + 4*l); }
        if (ok1) { g1a = *(const float4*)(r1 + 4*l); g1b = *(const float4*)(r1 + 256 + 4*l); }
        if (l < 9 && 512 + l < xlim) {
            if (ok0) g0t = r0[512 + l];
            if (ok1) g1t = r1[512 + l];
        }
    };

    auto lwrite = [&]() {
        *(float2*)&Ee[0][2*l]       = make_float2(g0a.x, g0a.z);
        *(float2*)&Oo[0][2*l]       = make_float2(g0a.y, g0a.w);
        *(float2*)&Ee[0][128 + 2*l] = make_float2(g0b.x, g0b.z);
        *(float2*)&Oo[0][128 + 2*l] = make_float2(g0b.y, g0b.w);
        *(float2*)&Ee[1][2*l]       = make_float2(g1a.x, g1a.z);
        *(float2*)&Oo[1][2*l]       = make_float2(g1a.y, g1a.w);
        *(float2*)&Ee[1][128 + 2*l] = make_float2(g1b.x, g1b.z);
        *(float2*)&Oo[1][128 + 2*l] = make_float2(g1b.y, g1b.w);
        if (l < 9) {                                    // words 512..520
            const int i = 256 + (l >> 1);
            if ((l & 1) == 0) { Ee[0][i] = g0t; Ee[1][i] = g1t; }
            else              { Oo[0][i] = g0t; Oo[1][i] = g1t; }
        }
    };

    gload(0);
    lwrite();

    #pragma unroll 1
    for (int g = 0; g < NPAIRG; ++g) {
        #pragma unroll
        for (int u = 0; u < 6; ++u) {
            const int p = 6*g + u;

            // span reads: 17 words per row at 16B/lane stride (conflict-free)
            float ev0[9], ov0[8], ev1[9], ov1[8];
            {
                const float4 a = *(const float4*)&Ee[0][4*l];
                const float4 b = *(const float4*)&Ee[0][4*l + 4];
                const float  t =                  Ee[0][4*l + 8];
                const float4 c = *(const float4*)&Oo[0][4*l];
                const float4 d = *(const float4*)&Oo[0][4*l + 4];
                ev0[0]=a.x; ev0[1]=a.y; ev0[2]=a.z; ev0[3]=a.w;
                ev0[4]=b.x; ev0[5]=b.y; ev0[6]=b.z; ev0[7]=b.w; ev0[8]=t;
                ov0[0]=c.x; ov0[1]=c.y; ov0[2]=c.z; ov0[3]=c.w;
                ov0[4]=d.x; ov0[5]=d.y; ov0[6]=d.z; ov0[7]=d.w;
            }
            {
                const float4 a = *(const float4*)&Ee[1][4*l];
                const float4 b = *(const float4*)&Ee[1][4*l + 4];
                const float  t =                  Ee[1][4*l + 8];
                const float4 c = *(const float4*)&Oo[1][4*l];
                const float4 d = *(const float4*)&Oo[1][4*l + 4];
                ev1[0]=a.x; ev1[1]=a.y; ev1[2]=a.z; ev1[3]=a.w; ev1[4]=b.x;
                ev1[5]=b.y; ev1[6]=b.z; ev1[7]=b.w; ev1[8]=t;
                ov1[0]=c.x; ov1[1]=c.y; ov1[2]=c.z; ov1[3]=c.w;
                ov1[4]=d.x; ov1[5]=d.y; ov1[6]=d.z; ov1[7]=d.w;
            }

            gload(p + 1);            // next pair in flight under the FMAs

            // even input row 2p: ky = 2a into slot (u+5-a)%6
            #pragma unroll
            for (int a = 0; a < 6; ++a) {
                const int s  = (u + 5 - a) % 6;
                const int ky = 2*a;
                #pragma unroll
                for (int m = 0; m < 6; ++m) {
                    const float w = kf[ky*KS + 2*m];
                    #pragma unroll
                    for (int j = 0; j < 4; ++j)
                        acc[s][j] = fmaf(ev0[m + j], w, acc[s][j]);
                }
                #pragma unroll
                for (int m = 0; m < 5; ++m) {
                    const float w = kf[ky*KS + 2*m + 1];
                    #pragma unroll
                    for (int j = 0; j < 4; ++j)
                        acc[s][j] = fmaf(ov0[m + j], w, acc[s][j]);
                }
            }
            // odd input row 2p+1: ky = 2a+1
            #pragma unroll
            for (int a = 0; a < 5; ++a) {
                const int s  = (u + 5 - a) % 6;
                const int ky = 2*a + 1;
                #pragma unroll
                for (int m = 0; m < 6; ++m) {
                    const float w = kf[ky*KS + 2*m];
                    #pragma unroll
                    for (int j = 0; j < 4; ++j)
                        acc[s][j] = fmaf(ev1[m + j], w, acc[s][j]);
                }
                #pragma unroll
                for (int m = 0; m < 5; ++m) {
                    const float w = kf[ky*KS + 2*m + 1];
                    #pragma unroll
                    for (int j = 0; j < 4; ++j)
                        acc[s][j] = fmaf(ov1[m + j], w, acc[s][j]);
                }
            }

            // slot u completes output row oy0 + p - 5
            if (p >= 5) {
                const int oy = oy0 + p - 5;
                if (oy < OW) {
                    float* op = outc + (size_t)oy * OW + ox0 + 4*l;
                    if (ox0 + 4*l + 3 < OW) {
                        op[0] = acc[u][0]; op[1] = acc[u][1];
                        op[2] = acc[u][2]; op[3] = acc[u][3];
                    } else {
                        #pragma unroll
                        for (int j = 0; j < 4; ++j)
                            if (ox0 + 4*l + j < OW) op[j] = acc[u][j];
                    }
                }
            }
            acc[u][0] = acc[u][1] = acc[u][2] = acc[u][3] = 0.f;

            lwrite();                // publish pair p+1 for next iteration
        }
    }
}

extern "C" void kernel_launch(void* const* d_in, const int* in_sizes, int n_in,
                              void* d_out, int out_size, void* d_ws, size_t ws_size,
                              hipStream_t stream)
{
    const float* in   = (const float*)d_in[0];
    const float* kc   = (const float*)d_in[1];
    const float* W1   = (const float*)d_in[2];
    const float* b1   = (const float*)d_in[3];
    const float* W2   = (const float*)d_in[4];
    const float* b2   = (const float*)d_in[5];
    const float* lg   = (const float*)d_in[6];
    const float* beta = (const float*)d_in[7];
    const float* mean = (const float*)d_in[8];
    const float* var  = (const float*)d_in[9];

    float* out  = (float*)d_out;
    float* kout = out + (size_t)3 * OW * OW;   // out_k lives at the tail of d_out

    flow_kernel<<<dim3(1), dim3(128), 0, stream>>>(kc, W1, b1, W2, b2, lg, beta, mean, var, kout);

    dim3 grid(8, (OW + HSTRIP - 1) / HSTRIP, 3);
    conv_kernel<<<grid, dim3(64), 0, stream>>>(in, kout, out);
}

// Round 18
// 209.939 us; speedup vs baseline: 1.4443x; 1.4443x over previous
//
#include <hip/hip_runtime.h>

#define DD   121
#define NHID 15
#define NBLK 5
#define KS   11
#define IW   4096
#define OW   2043

// DPP row-rotate add: v += rotate_within_16_lane_row(v, N). VALU-only reduce.
#define ROR_ADD(v, N)                                                         \
  v += __int_as_float(__builtin_amdgcn_update_dpp(                            \
      0, __float_as_int(v), 0x120 + (N), 0xF, 0xF, true))

// Packed staging: W1 direct; W2 as per-idx (m,a) pairs; b2 as (m,a) pairs.
__device__ __forceinline__ void stage_weights(
    float* W1d, float* W2d, float* b2d, float* b1d,
    const float* __restrict__ W1, const float* __restrict__ W2,
    const float* __restrict__ b2, const float* __restrict__ b1,
    int blk, int t0, int nt)
{
    const float* W1b = W1 + blk * NHID * DD;
    const float* W2b = W2 + blk * 2 * DD * NHID;
    const float* b2b = b2 + blk * 2 * DD;
    for (int i = t0; i < NHID * DD; i += nt) W1d[i] = W1b[i];   // [j*DD+idx]
    for (int k = t0; k < DD * NHID; k += nt) {
        const int idx = k / NHID, j = k - idx * NHID;
        W2d[idx*32 + 2*j]     = W2b[idx*NHID + j];         // m-weight
        W2d[idx*32 + 2*j + 1] = W2b[(DD + idx)*NHID + j];  // loga-weight
    }
    for (int i = t0; i < DD; i += nt) {
        W2d[i*32 + 30] = 0.f;                              // pad lane 15
        W2d[i*32 + 31] = 0.f;
        b2d[2*i]     = b2b[i];
        b2d[2*i + 1] = b2b[DD + i];
    }
    for (int i = t0; i < NHID; i += nt) b1d[i] = b1[blk*NHID + i];
}

// ---------------------------------------------------------------------------
// Flow inverse (MAF) + post-process. 2 waves: wave0 scans (lanes 0..15, DPP
// reduce, 4-slot named-register prefetch distance 4), wave1 stages next
// block's weights into the other LDS buffer. (unchanged from r11-r13)
// ---------------------------------------------------------------------------
__global__ __launch_bounds__(128) void flow_kernel(
    const float* __restrict__ kc,
    const float* __restrict__ W1, const float* __restrict__ b1,
    const float* __restrict__ W2, const float* __restrict__ b2,
    const float* __restrict__ lg, const float* __restrict__ beta,
    const float* __restrict__ mean, const float* __restrict__ var,
    float* __restrict__ kout)
{
    __shared__ float xs[DD];
    __shared__ float us[DD];
    __shared__ float W1s[2][NHID * DD];
    __shared__ float W2p[2][DD * 32];     // [idx*32 + 2j] = (m, a) pair
    __shared__ float b2p[2][DD * 2];      // [2*idx] = (m, a) pair
    __shared__ float b1s[2][16];

    const int tid  = threadIdx.x;
    const int wv   = tid >> 6;
    const int lane = tid & 63;

    stage_weights(W1s[0], W2p[0], b2p[0], b1s[0], W1, W2, b2, b1, NBLK - 1, tid, 128);
    if (tid < DD) xs[tid] = kc[tid];
    __syncthreads();

    for (int b = NBLK - 1; b >= 0; --b) {
        const int buf = (NBLK - 1 - b) & 1;
        if (wv == 1) {
            if (b > 0)
                stage_weights(W1s[buf^1], W2p[buf^1], b2p[buf^1], b1s[buf^1],
                              W1, W2, b2, b1, b - 1, lane, 64);
        } else {
            // BatchNorm inverse (eval): x = (x-beta)*exp(-lg)*sqrt(var+eps)+mean
            for (int i = lane; i < DD; i += 64) {
                float s = sqrtf(var[b*DD + i] + 1e-5f);
                us[i] = (xs[i] - beta[b*DD + i]) * __expf(-lg[b*DD + i]) * s + mean[b*DD + i];
            }
            const int evenb = ((b & 1) == 0);
            if (lane < 16) {
                const int j  = lane;
                const int jc = (j < NHID) ? j : (NHID - 1);   // clamp W1 row addr
                float pre_h = (j < NHID) ? b1s[buf][j] : 0.f;

                auto step = [&](int t, int iS, float2 wpS, float w1S, float uvS, float2 bpS) {
                    float h  = (j < t && j < NHID) ? fmaxf(pre_h, 0.f) : 0.f;
                    float pm = h * wpS.x;
                    float pa = h * wpS.y;
                    ROR_ADD(pm, 1); ROR_ADD(pa, 1);
                    ROR_ADD(pm, 2); ROR_ADD(pa, 2);
                    ROR_ADD(pm, 4); ROR_ADD(pa, 4);
                    ROR_ADD(pm, 8); ROR_ADD(pa, 8);
                    const float xv = fmaf(uvS, __expf(pa + bpS.y), pm + bpS.x);
                    if (j >= t && j < NHID) pre_h = fmaf(xv, w1S, pre_h);
                    if (j == 0) xs[iS] = xv;
                };

                int iA, iB, iC, iD;
                float2 wpA, wpB, wpC, wpD, bpA, bpB, bpC, bpD;
                float  w1A, w1B, w1C, w1D, uvA, uvB, uvC, uvD;

                #define PRELOAD(S, T) { const int tt = (T);                                 \
                    i##S  = evenb ? tt : (DD - 1 - tt);                                     \
                    wp##S = *(const float2*)&W2p[buf][i##S*32 + 2*j];                       \
                    w1##S = W1s[buf][jc*DD + i##S];                                         \
                    uv##S = us[i##S];                                                       \
                    bp##S = *(const float2*)&b2p[buf][2*i##S]; }

                #define QSTEP(S, TCUR, TNEXT) {                                             \
                    int tt = (TNEXT); if (tt > DD - 1) tt = DD - 1;                         \
                    const int ip = evenb ? tt : (DD - 1 - tt);                              \
                    const float2 wpN = *(const float2*)&W2p[buf][ip*32 + 2*j];              \
                    const float  w1N = W1s[buf][jc*DD + ip];                                \
                    const float  uvN = us[ip];                                              \
                    const float2 bpN = *(const float2*)&b2p[buf][2*ip];                     \
                    step((TCUR), i##S, wp##S, w1##S, uv##S, bp##S);                         \
                    i##S = ip; wp##S = wpN; w1##S = w1N; uv##S = uvN; bp##S = bpN; }

                PRELOAD(A, 0) PRELOAD(B, 1) PRELOAD(C, 2) PRELOAD(D, 3)
                #pragma unroll 1
                for (int it = 0; it < 30; ++it) {        // t = 4it .. 4it+3; DD-1=120=4*30
                    QSTEP(A, 4*it + 0, 4*it + 4)
                    QSTEP(B, 4*it + 1, 4*it + 5)
                    QSTEP(C, 4*it + 2, 4*it + 6)
                    QSTEP(D, 4*it + 3, 4*it + 7)
                }
                step(DD - 1, iA, wpA, w1A, uvA, bpA);    // final step t=120
                #undef PRELOAD
                #undef QSTEP
            }
        }
        __syncthreads();
    }

    // post-process: y = (sigmoid(x)-a)/(1-2a); k = y/sum(y)
    if (tid < 64) {
        const float A = 1e-6f;
        float y0, y1 = 0.f;
        {
            float v = xs[tid];
            y0 = (1.f / (1.f + __expf(-v)) - A) / (1.f - 2.f*A);
        }
        if (tid + 64 < DD) {
            float v = xs[tid + 64];
            y1 = (1.f / (1.f + __expf(-v)) - A) / (1.f - 2.f*A);
        }
        float s = y0 + y1;
        #pragma unroll
        for (int off = 32; off >= 1; off >>= 1) s += __shfl_xor(s, off, 64);
        kout[tid] = y0 / s;
        if (tid + 64 < DD) kout[tid + 64] = y1 / s;
    }
}

// ---------------------------------------------------------------------------
// DIRECT (no-LDS) 11x11 stride-2 conv. Block = 256 threads = one 2048-wide
// x 2-row output stripe; thread tx computes 8 outputs ox=8tx..8tx+7 for both
// rows. Per input row: 7 global_load_dwordx4 (28 words; even/odd selection is
// static register indexing wv[2j+kx] -- no parity-split, no LDS, no barriers,
// no bank conflicts). y-amplification 13/4 = 3.25x -> ~650MB L2 traffic
// (~19us @34.5TB/s); VALU 19us; HBM ~20us (L3-warm) -- all overlap at high
// occupancy (VGPR ~70, no LDS). Bijective XCD swizzle on the y-stripe index
// keeps the 9-row overlap of consecutive stripes in one XCD's L2 (m204).
// ---------------------------------------------------------------------------
__global__ __launch_bounds__(256) void conv_kernel(
    const float* __restrict__ in, const float* __restrict__ kf,
    float* __restrict__ out)
{
    const int tx = threadIdx.x;          // 0..255
    int py = blockIdx.x;                 // y-stripe 0..1021 (pre-swizzle)
    {
        const int N = (OW + 1) / 2;      // 1022
        const int q = N / 8, r = N % 8;  // 127, 6
        const int xcd = py & 7, idx = py >> 3;
        py = (xcd < r) ? xcd * (q + 1) + idx
                       : r * (q + 1) + (xcd - r) * q + idx;
    }
    const int ch  = blockIdx.y;
    const int oy0 = 2 * py;
    const int gy0 = 4 * py;

    const float* __restrict__ inc  = in  + (size_t)ch * IW * IW;
    float*       __restrict__ outc = out + (size_t)ch * OW * OW;
    const int wbase = 16 * tx;           // input word base for this thread

    float acc0[8] = {0.f,0.f,0.f,0.f,0.f,0.f,0.f,0.f};
    float acc1[8] = {0.f,0.f,0.f,0.f,0.f,0.f,0.f,0.f};

    #pragma unroll 1
    for (int iy = 0; iy < 13; ++iy) {
        const int gy = gy0 + iy;
        if (gy >= IW) break;             // uniform (only last stripe)
        const float* rp = inc + (size_t)gy * IW + wbase;

        float4 w0, w1, w2, w3, w4, w5, w6;
        if (tx < 255) {                  // full 28-word span in bounds
            w0 = *(const float4*)(rp);      w1 = *(const float4*)(rp + 4);
            w2 = *(const float4*)(rp + 8);  w3 = *(const float4*)(rp + 12);
            w4 = *(const float4*)(rp + 16); w5 = *(const float4*)(rp + 20);
            w6 = *(const float4*)(rp + 24);
        } else {                         // tail thread: words 4080..4095 only
            w0 = *(const float4*)(rp);      w1 = *(const float4*)(rp + 4);
            w2 = *(const float4*)(rp + 8);  w3 = *(const float4*)(rp + 12);
            w4 = make_float4(0.f,0.f,0.f,0.f); w5 = w4; w6 = w4;
        }
        float wv[28];
        wv[0]=w0.x;  wv[1]=w0.y;  wv[2]=w0.z;  wv[3]=w0.w;
        wv[4]=w1.x;  wv[5]=w1.y;  wv[6]=w1.z;  wv[7]=w1.w;
        wv[8]=w2.x;  wv[9]=w2.y;  wv[10]=w2.z; wv[11]=w2.w;
        wv[12]=w3.x; wv[13]=w3.y; wv[14]=w3.z; wv[15]=w3.w;
        wv[16]=w4.x; wv[17]=w4.y; wv[18]=w4.z; wv[19]=w4.w;
        wv[20]=w5.x; wv[21]=w5.y; wv[22]=w5.z; wv[23]=w5.w;
        wv[24]=w6.x; wv[25]=w6.y; wv[26]=w6.z; wv[27]=w6.w;

        if (iy <= 10) {                  // contributes ky=iy to output row oy0
            const float* kr = kf + iy * KS;
            #pragma unroll
            for (int kx = 0; kx < 11; ++kx) {
                const float kw = kr[kx];            // uniform -> s_load
                #pragma unroll
                for (int j = 0; j < 8; ++j)
                    acc0[j] = fmaf(wv[2*j + kx], kw, acc0[j]);
            }
        }
        if (iy >= 2) {                   // contributes ky=iy-2 to row oy0+1
            const float* kr = kf + (iy - 2) * KS;
            #pragma unroll
            for (int kx = 0; kx < 11; ++kx) {
                const float kw = kr[kx];            // uniform -> s_load
                #pragma unroll
                for (int j = 0; j < 8; ++j)
                    acc1[j] = fmaf(wv[2*j + kx], kw, acc1[j]);
            }
        }
    }

    const int ox0 = 8 * tx;
    {
        float* op = outc + (size_t)oy0 * OW + ox0;
        #pragma unroll
        for (int j = 0; j < 8; ++j)
            if (ox0 + j < OW) op[j] = acc0[j];
    }
    if (oy0 + 1 < OW) {
        float* op = outc + (size_t)(oy0 + 1) * OW + ox0;
        #pragma unroll
        for (int j = 0; j < 8; ++j)
            if (ox0 + j < OW) op[j] = acc1[j];
    }
}

extern "C" void kernel_launch(void* const* d_in, const int* in_sizes, int n_in,
                              void* d_out, int out_size, void* d_ws, size_t ws_size,
                              hipStream_t stream)
{
    const float* in   = (const float*)d_in[0];
    const float* kc   = (const float*)d_in[1];
    const float* W1   = (const float*)d_in[2];
    const float* b1   = (const float*)d_in[3];
    const float* W2   = (const float*)d_in[4];
    const float* b2   = (const float*)d_in[5];
    const float* lg   = (const float*)d_in[6];
    const float* beta = (const float*)d_in[7];
    const float* mean = (const float*)d_in[8];
    const float* var  = (const float*)d_in[9];

    float* out  = (float*)d_out;
    float* kout = out + (size_t)3 * OW * OW;   // out_k lives at the tail of d_out

    flow_kernel<<<dim3(1), dim3(128), 0, stream>>>(kc, W1, b1, W2, b2, lg, beta, mean, var, kout);

    dim3 grid((OW + 1) / 2, 3);
    conv_kernel<<<grid, dim3(256), 0, stream>>>(in, kout, out);
}

// Round 19
// 203.437 us; speedup vs baseline: 1.4905x; 1.0320x over previous
//
#include <hip/hip_runtime.h>

#define DD   121
#define NHID 15
#define NBLK 5
#define KS   11
#define IW   4096
#define OW   2043

// DPP row-rotate add: v += rotate_within_16_lane_row(v, N). VALU-only reduce.
#define ROR_ADD(v, N)                                                         \
  v += __int_as_float(__builtin_amdgcn_update_dpp(                            \
      0, __float_as_int(v), 0x120 + (N), 0xF, 0xF, true))

// Packed staging: W1 direct; W2 as per-idx (m,a) pairs; b2 as (m,a) pairs.
__device__ __forceinline__ void stage_weights(
    float* W1d, float* W2d, float* b2d, float* b1d,
    const float* __restrict__ W1, const float* __restrict__ W2,
    const float* __restrict__ b2, const float* __restrict__ b1,
    int blk, int t0, int nt)
{
    const float* W1b = W1 + blk * NHID * DD;
    const float* W2b = W2 + blk * 2 * DD * NHID;
    const float* b2b = b2 + blk * 2 * DD;
    for (int i = t0; i < NHID * DD; i += nt) W1d[i] = W1b[i];   // [j*DD+idx]
    for (int k = t0; k < DD * NHID; k += nt) {
        const int idx = k / NHID, j = k - idx * NHID;
        W2d[idx*32 + 2*j]     = W2b[idx*NHID + j];         // m-weight
        W2d[idx*32 + 2*j + 1] = W2b[(DD + idx)*NHID + j];  // loga-weight
    }
    for (int i = t0; i < DD; i += nt) {
        W2d[i*32 + 30] = 0.f;                              // pad lane 15
        W2d[i*32 + 31] = 0.f;
        b2d[2*i]     = b2b[i];
        b2d[2*i + 1] = b2b[DD + i];
    }
    for (int i = t0; i < NHID; i += nt) b1d[i] = b1[blk*NHID + i];
}

// ---------------------------------------------------------------------------
// Flow inverse (MAF) + post-process. 2 waves: wave0 scans (lanes 0..15, DPP
// reduce, 4-slot named-register prefetch distance 4), wave1 stages next
// block's weights into the other LDS buffer. (unchanged from r11-r18)
// ---------------------------------------------------------------------------
__global__ __launch_bounds__(128) void flow_kernel(
    const float* __restrict__ kc,
    const float* __restrict__ W1, const float* __restrict__ b1,
    const float* __restrict__ W2, const float* __restrict__ b2,
    const float* __restrict__ lg, const float* __restrict__ beta,
    const float* __restrict__ mean, const float* __restrict__ var,
    float* __restrict__ kout)
{
    __shared__ float xs[DD];
    __shared__ float us[DD];
    __shared__ float W1s[2][NHID * DD];
    __shared__ float W2p[2][DD * 32];     // [idx*32 + 2j] = (m, a) pair
    __shared__ float b2p[2][DD * 2];      // [2*idx] = (m, a) pair
    __shared__ float b1s[2][16];

    const int tid  = threadIdx.x;
    const int wv   = tid >> 6;
    const int lane = tid & 63;

    stage_weights(W1s[0], W2p[0], b2p[0], b1s[0], W1, W2, b2, b1, NBLK - 1, tid, 128);
    if (tid < DD) xs[tid] = kc[tid];
    __syncthreads();

    for (int b = NBLK - 1; b >= 0; --b) {
        const int buf = (NBLK - 1 - b) & 1;
        if (wv == 1) {
            if (b > 0)
                stage_weights(W1s[buf^1], W2p[buf^1], b2p[buf^1], b1s[buf^1],
                              W1, W2, b2, b1, b - 1, lane, 64);
        } else {
            // BatchNorm inverse (eval): x = (x-beta)*exp(-lg)*sqrt(var+eps)+mean
            for (int i = lane; i < DD; i += 64) {
                float s = sqrtf(var[b*DD + i] + 1e-5f);
                us[i] = (xs[i] - beta[b*DD + i]) * __expf(-lg[b*DD + i]) * s + mean[b*DD + i];
            }
            const int evenb = ((b & 1) == 0);
            if (lane < 16) {
                const int j  = lane;
                const int jc = (j < NHID) ? j : (NHID - 1);   // clamp W1 row addr
                float pre_h = (j < NHID) ? b1s[buf][j] : 0.f;

                auto step = [&](int t, int iS, float2 wpS, float w1S, float uvS, float2 bpS) {
                    float h  = (j < t && j < NHID) ? fmaxf(pre_h, 0.f) : 0.f;
                    float pm = h * wpS.x;
                    float pa = h * wpS.y;
                    ROR_ADD(pm, 1); ROR_ADD(pa, 1);
                    ROR_ADD(pm, 2); ROR_ADD(pa, 2);
                    ROR_ADD(pm, 4); ROR_ADD(pa, 4);
                    ROR_ADD(pm, 8); ROR_ADD(pa, 8);
                    const float xv = fmaf(uvS, __expf(pa + bpS.y), pm + bpS.x);
                    if (j >= t && j < NHID) pre_h = fmaf(xv, w1S, pre_h);
                    if (j == 0) xs[iS] = xv;
                };

                int iA, iB, iC, iD;
                float2 wpA, wpB, wpC, wpD, bpA, bpB, bpC, bpD;
                float  w1A, w1B, w1C, w1D, uvA, uvB, uvC, uvD;

                #define PRELOAD(S, T) { const int tt = (T);                                 \
                    i##S  = evenb ? tt : (DD - 1 - tt);                                     \
                    wp##S = *(const float2*)&W2p[buf][i##S*32 + 2*j];                       \
                    w1##S = W1s[buf][jc*DD + i##S];                                         \
                    uv##S = us[i##S];                                                       \
                    bp##S = *(const float2*)&b2p[buf][2*i##S]; }

                #define QSTEP(S, TCUR, TNEXT) {                                             \
                    int tt = (TNEXT); if (tt > DD - 1) tt = DD - 1;                         \
                    const int ip = evenb ? tt : (DD - 1 - tt);                              \
                    const float2 wpN = *(const float2*)&W2p[buf][ip*32 + 2*j];              \
                    const float  w1N = W1s[buf][jc*DD + ip];                                \
                    const float  uvN = us[ip];                                              \
                    const float2 bpN = *(const float2*)&b2p[buf][2*ip];                     \
                    step((TCUR), i##S, wp##S, w1##S, uv##S, bp##S);                         \
                    i##S = ip; wp##S = wpN; w1##S = w1N; uv##S = uvN; bp##S = bpN; }

                PRELOAD(A, 0) PRELOAD(B, 1) PRELOAD(C, 2) PRELOAD(D, 3)
                #pragma unroll 1
                for (int it = 0; it < 30; ++it) {        // t = 4it .. 4it+3; DD-1=120=4*30
                    QSTEP(A, 4*it + 0, 4*it + 4)
                    QSTEP(B, 4*it + 1, 4*it + 5)
                    QSTEP(C, 4*it + 2, 4*it + 6)
                    QSTEP(D, 4*it + 3, 4*it + 7)
                }
                step(DD - 1, iA, wpA, w1A, uvA, bpA);    // final step t=120
                #undef PRELOAD
                #undef QSTEP
            }
        }
        __syncthreads();
    }

    // post-process: y = (sigmoid(x)-a)/(1-2a); k = y/sum(y)
    if (tid < 64) {
        const float A = 1e-6f;
        float y0, y1 = 0.f;
        {
            float v = xs[tid];
            y0 = (1.f / (1.f + __expf(-v)) - A) / (1.f - 2.f*A);
        }
        if (tid + 64 < DD) {
            float v = xs[tid + 64];
            y1 = (1.f / (1.f + __expf(-v)) - A) / (1.f - 2.f*A);
        }
        float s = y0 + y1;
        #pragma unroll
        for (int off = 32; off >= 1; off >>= 1) s += __shfl_xor(s, off, 64);
        kout[tid] = y0 / s;
        if (tid + 64 < DD) kout[tid + 64] = y1 / s;
    }
}

// ---------------------------------------------------------------------------
// DIRECT (no-LDS) 11x11 stride-2 conv, 2-DEEP LOAD PIPELINE.
// Block = 256 threads = one 2048-wide x 2-row output stripe; thread tx
// computes 8 outputs ox=8tx..8tx+7 for both rows. Per input row: 7
// global_load_dwordx4 into NAMED float4 slots; row iy+1's loads are issued
// BEFORE row iy's FMAs (r18 diagnosis: unroll-1 serialized 13 full
// vmcnt(0)+HBM-latency drains -> VALUBusy 27%). Zero LDS, zero barriers,
// zero bank conflicts (r18 measured). Ghost rows (gy>=IW) zero-filled; they
// only feed the guarded-out oy0+1 store on the last stripe.
// Bijective XCD swizzle on the y-stripe index (m204) for L2 row-overlap reuse.
// ---------------------------------------------------------------------------
__global__ __launch_bounds__(256) void conv_kernel(
    const float* __restrict__ in, const float* __restrict__ kf,
    float* __restrict__ out)
{
    const int tx = threadIdx.x;          // 0..255
    int py = blockIdx.x;                 // y-stripe 0..1021 (pre-swizzle)
    {
        const int N = (OW + 1) / 2;      // 1022
        const int q = N / 8, r = N % 8;  // 127, 6
        const int xcd = py & 7, idx = py >> 3;
        py = (xcd < r) ? xcd * (q + 1) + idx
                       : r * (q + 1) + (xcd - r) * q + idx;
    }
    const int ch  = blockIdx.y;
    const int oy0 = 2 * py;
    const int gy0 = 4 * py;

    const float* __restrict__ inc  = in  + (size_t)ch * IW * IW;
    float*       __restrict__ outc = out + (size_t)ch * OW * OW;
    const int wbase = 16 * tx;           // input word base for this thread

    float acc0[8] = {0.f,0.f,0.f,0.f,0.f,0.f,0.f,0.f};
    float acc1[8] = {0.f,0.f,0.f,0.f,0.f,0.f,0.f,0.f};

    float4 A0, A1, A2, A3, A4, A5, A6;
    float4 B0, B1, B2, B3, B4, B5, B6;

    #define GLOAD(IY, S0, S1, S2, S3, S4, S5, S6) {                           \
        const int gy_ = gy0 + (IY);                                           \
        const float4 z_ = make_float4(0.f, 0.f, 0.f, 0.f);                    \
        S0 = z_; S1 = z_; S2 = z_; S3 = z_; S4 = z_; S5 = z_; S6 = z_;        \
        if (gy_ < IW) {                                                       \
            const float* rp_ = inc + (size_t)gy_ * IW + wbase;                \
            S0 = *(const float4*)(rp_);      S1 = *(const float4*)(rp_ + 4);  \
            S2 = *(const float4*)(rp_ + 8);  S3 = *(const float4*)(rp_ + 12); \
            if (tx < 255) {                                                   \
                S4 = *(const float4*)(rp_ + 16);                              \
                S5 = *(const float4*)(rp_ + 20);                              \
                S6 = *(const float4*)(rp_ + 24);                              \
            }                                                                 \
        } }

    #define COMPUTE(IY, S0, S1, S2, S3, S4, S5, S6) {                         \
        const float wv[28] = {S0.x,S0.y,S0.z,S0.w, S1.x,S1.y,S1.z,S1.w,       \
                              S2.x,S2.y,S2.z,S2.w, S3.x,S3.y,S3.z,S3.w,       \
                              S4.x,S4.y,S4.z,S4.w, S5.x,S5.y,S5.z,S5.w,       \
                              S6.x,S6.y,S6.z,S6.w};                           \
        const int iy_ = (IY);                                                 \
        if (iy_ <= 10) {                 /* ky=iy -> row oy0 */               \
            const float* kr_ = kf + iy_ * KS;                                 \
            _Pragma("unroll")                                                 \
            for (int kx = 0; kx < 11; ++kx) {                                 \
                const float kw_ = kr_[kx];                                    \
                _Pragma("unroll")                                             \
                for (int j = 0; j < 8; ++j)                                   \
                    acc0[j] = fmaf(wv[2*j + kx], kw_, acc0[j]);               \
            }                                                                 \
        }                                                                     \
        if (iy_ >= 2) {                  /* ky=iy-2 -> row oy0+1 */           \
            const float* kr_ = kf + (iy_ - 2) * KS;                           \
            _Pragma("unroll")                                                 \
            for (int kx = 0; kx < 11; ++kx) {                                 \
                const float kw_ = kr_[kx];                                    \
                _Pragma("unroll")                                             \
                for (int j = 0; j < 8; ++j)                                   \
                    acc1[j] = fmaf(wv[2*j + kx], kw_, acc1[j]);               \
            }                                                                 \
        } }

    GLOAD(0, A0, A1, A2, A3, A4, A5, A6)
    #pragma unroll 1
    for (int it = 0; it < 6; ++it) {     // iy = 2it, 2it+1 ; iy in 0..11
        const int iy = 2 * it;
        GLOAD(iy + 1, B0, B1, B2, B3, B4, B5, B6)   // in flight under COMPUTE(A)
        COMPUTE(iy, A0, A1, A2, A3, A4, A5, A6)
        GLOAD(iy + 2, A0, A1, A2, A3, A4, A5, A6)   // in flight under COMPUTE(B)
        COMPUTE(iy + 1, B0, B1, B2, B3, B4, B5, B6)
    }
    COMPUTE(12, A0, A1, A2, A3, A4, A5, A6)
    #undef GLOAD
    #undef COMPUTE

    const int ox0 = 8 * tx;
    {
        float* op = outc + (size_t)oy0 * OW + ox0;
        #pragma unroll
        for (int j = 0; j < 8; ++j)
            if (ox0 + j < OW) op[j] = acc0[j];
    }
    if (oy0 + 1 < OW) {
        float* op = outc + (size_t)(oy0 + 1) * OW + ox0;
        #pragma unroll
        for (int j = 0; j < 8; ++j)
            if (ox0 + j < OW) op[j] = acc1[j];
    }
}

extern "C" void kernel_launch(void* const* d_in, const int* in_sizes, int n_in,
                              void* d_out, int out_size, void* d_ws, size_t ws_size,
                              hipStream_t stream)
{
    const float* in   = (const float*)d_in[0];
    const float* kc   = (const float*)d_in[1];
    const float* W1   = (const float*)d_in[2];
    const float* b1   = (const float*)d_in[3];
    const float* W2   = (const float*)d_in[4];
    const float* b2   = (const float*)d_in[5];
    const float* lg   = (const float*)d_in[6];
    const float* beta = (const float*)d_in[7];
    const float* mean = (const float*)d_in[8];
    const float* var  = (const float*)d_in[9];

    float* out  = (float*)d_out;
    float* kout = out + (size_t)3 * OW * OW;   // out_k lives at the tail of d_out

    flow_kernel<<<dim3(1), dim3(128), 0, stream>>>(kc, W1, b1, W2, b2, lg, beta, mean, var, kout);

    dim3 grid((OW + 1) / 2, 3);
    conv_kernel<<<grid, dim3(256), 0, stream>>>(in, kout, out);
}

// Round 20
// 189.462 us; speedup vs baseline: 1.6004x; 1.0738x over previous
//
#include <hip/hip_runtime.h>

#define DD   121
#define NHID 15
#define NBLK 5
#define KS   11
#define IW   4096
#define OW   2043

// DPP row-rotate add: v += rotate_within_16_lane_row(v, N). VALU-only reduce.
#define ROR_ADD(v, N)                                                         \
  v += __int_as_float(__builtin_amdgcn_update_dpp(                            \
      0, __float_as_int(v), 0x120 + (N), 0xF, 0xF, true))

// Packed staging: W1 direct; W2 as per-idx (m,a) pairs; b2 as (m,a) pairs.
__device__ __forceinline__ void stage_weights(
    float* W1d, float* W2d, float* b2d, float* b1d,
    const float* __restrict__ W1, const float* __restrict__ W2,
    const float* __restrict__ b2, const float* __restrict__ b1,
    int blk, int t0, int nt)
{
    const float* W1b = W1 + blk * NHID * DD;
    const float* W2b = W2 + blk * 2 * DD * NHID;
    const float* b2b = b2 + blk * 2 * DD;
    for (int i = t0; i < NHID * DD; i += nt) W1d[i] = W1b[i];   // [j*DD+idx]
    for (int k = t0; k < DD * NHID; k += nt) {
        const int idx = k / NHID, j = k - idx * NHID;
        W2d[idx*32 + 2*j]     = W2b[idx*NHID + j];         // m-weight
        W2d[idx*32 + 2*j + 1] = W2b[(DD + idx)*NHID + j];  // loga-weight
    }
    for (int i = t0; i < DD; i += nt) {
        W2d[i*32 + 30] = 0.f;                              // pad lane 15
        W2d[i*32 + 31] = 0.f;
        b2d[2*i]     = b2b[i];
        b2d[2*i + 1] = b2b[DD + i];
    }
    for (int i = t0; i < NHID; i += nt) b1d[i] = b1[blk*NHID + i];
}

// ---------------------------------------------------------------------------
// Flow inverse (MAF) + post-process. 2 waves: wave0 scans (lanes 0..15, DPP
// reduce, 4-slot named-register prefetch distance 4), wave1 stages next
// block's weights into the other LDS buffer. (unchanged from r11-r19)
// ---------------------------------------------------------------------------
__global__ __launch_bounds__(128) void flow_kernel(
    const float* __restrict__ kc,
    const float* __restrict__ W1, const float* __restrict__ b1,
    const float* __restrict__ W2, const float* __restrict__ b2,
    const float* __restrict__ lg, const float* __restrict__ beta,
    const float* __restrict__ mean, const float* __restrict__ var,
    float* __restrict__ kout)
{
    __shared__ float xs[DD];
    __shared__ float us[DD];
    __shared__ float W1s[2][NHID * DD];
    __shared__ float W2p[2][DD * 32];     // [idx*32 + 2j] = (m, a) pair
    __shared__ float b2p[2][DD * 2];      // [2*idx] = (m, a) pair
    __shared__ float b1s[2][16];

    const int tid  = threadIdx.x;
    const int wv   = tid >> 6;
    const int lane = tid & 63;

    stage_weights(W1s[0], W2p[0], b2p[0], b1s[0], W1, W2, b2, b1, NBLK - 1, tid, 128);
    if (tid < DD) xs[tid] = kc[tid];
    __syncthreads();

    for (int b = NBLK - 1; b >= 0; --b) {
        const int buf = (NBLK - 1 - b) & 1;
        if (wv == 1) {
            if (b > 0)
                stage_weights(W1s[buf^1], W2p[buf^1], b2p[buf^1], b1s[buf^1],
                              W1, W2, b2, b1, b - 1, lane, 64);
        } else {
            // BatchNorm inverse (eval): x = (x-beta)*exp(-lg)*sqrt(var+eps)+mean
            for (int i = lane; i < DD; i += 64) {
                float s = sqrtf(var[b*DD + i] + 1e-5f);
                us[i] = (xs[i] - beta[b*DD + i]) * __expf(-lg[b*DD + i]) * s + mean[b*DD + i];
            }
            const int evenb = ((b & 1) == 0);
            if (lane < 16) {
                const int j  = lane;
                const int jc = (j < NHID) ? j : (NHID - 1);   // clamp W1 row addr
                float pre_h = (j < NHID) ? b1s[buf][j] : 0.f;

                auto step = [&](int t, int iS, float2 wpS, float w1S, float uvS, float2 bpS) {
                    float h  = (j < t && j < NHID) ? fmaxf(pre_h, 0.f) : 0.f;
                    float pm = h * wpS.x;
                    float pa = h * wpS.y;
                    ROR_ADD(pm, 1); ROR_ADD(pa, 1);
                    ROR_ADD(pm, 2); ROR_ADD(pa, 2);
                    ROR_ADD(pm, 4); ROR_ADD(pa, 4);
                    ROR_ADD(pm, 8); ROR_ADD(pa, 8);
                    const float xv = fmaf(uvS, __expf(pa + bpS.y), pm + bpS.x);
                    if (j >= t && j < NHID) pre_h = fmaf(xv, w1S, pre_h);
                    if (j == 0) xs[iS] = xv;
                };

                int iA, iB, iC, iD;
                float2 wpA, wpB, wpC, wpD, bpA, bpB, bpC, bpD;
                float  w1A, w1B, w1C, w1D, uvA, uvB, uvC, uvD;

                #define PRELOAD(S, T) { const int tt = (T);                                 \
                    i##S  = evenb ? tt : (DD - 1 - tt);                                     \
                    wp##S = *(const float2*)&W2p[buf][i##S*32 + 2*j];                       \
                    w1##S = W1s[buf][jc*DD + i##S];                                         \
                    uv##S = us[i##S];                                                       \
                    bp##S = *(const float2*)&b2p[buf][2*i##S]; }

                #define QSTEP(S, TCUR, TNEXT) {                                             \
                    int tt = (TNEXT); if (tt > DD - 1) tt = DD - 1;                         \
                    const int ip = evenb ? tt : (DD - 1 - tt);                              \
                    const float2 wpN = *(const float2*)&W2p[buf][ip*32 + 2*j];              \
                    const float  w1N = W1s[buf][jc*DD + ip];                                \
                    const float  uvN = us[ip];                                              \
                    const float2 bpN = *(const float2*)&b2p[buf][2*ip];                     \
                    step((TCUR), i##S, wp##S, w1##S, uv##S, bp##S);                         \
                    i##S = ip; wp##S = wpN; w1##S = w1N; uv##S = uvN; bp##S = bpN; }

                PRELOAD(A, 0) PRELOAD(B, 1) PRELOAD(C, 2) PRELOAD(D, 3)
                #pragma unroll 1
                for (int it = 0; it < 30; ++it) {        // t = 4it .. 4it+3; DD-1=120=4*30
                    QSTEP(A, 4*it + 0, 4*it + 4)
                    QSTEP(B, 4*it + 1, 4*it + 5)
                    QSTEP(C, 4*it + 2, 4*it + 6)
                    QSTEP(D, 4*it + 3, 4*it + 7)
                }
                step(DD - 1, iA, wpA, w1A, uvA, bpA);    // final step t=120
                #undef PRELOAD
                #undef QSTEP
            }
        }
        __syncthreads();
    }

    // post-process: y = (sigmoid(x)-a)/(1-2a); k = y/sum(y)
    if (tid < 64) {
        const float A = 1e-6f;
        float y0, y1 = 0.f;
        {
            float v = xs[tid];
            y0 = (1.f / (1.f + __expf(-v)) - A) / (1.f - 2.f*A);
        }
        if (tid + 64 < DD) {
            float v = xs[tid + 64];
            y1 = (1.f / (1.f + __expf(-v)) - A) / (1.f - 2.f*A);
        }
        float s = y0 + y1;
        #pragma unroll
        for (int off = 32; off >= 1; off >>= 1) s += __shfl_xor(s, off, 64);
        kout[tid] = y0 / s;
        if (tid + 64 < DD) kout[tid + 64] = y1 / s;
    }
}

// ---------------------------------------------------------------------------
// COLUMN-SWEEP RING 11x11 stride-2 conv. No LDS, no barriers.
// Lane l owns 2 output cols c0=ox0+2l, c0+1 and sweeps 16 output rows.
// Per input-row PAIR: 8 float4 loads at 16B LANE STRIDE (fully coalesced:
// 64x16B = contiguous 1KB = 16 lines/instr; r18/r19's 64B-stride loads hit
// 64 lines/instr -- the measured occupancy-invariant ~155us transaction wall).
// 6-slot per-lane ring accumulator (float2 x 6, static idx via 6-unroll):
// pair t's even row feeds ky=2a to slots (t-a)%6 (a=0..5), odd row ky=2a+1
// (a=0..4); slot (t+1)%6 completes output row oy0+t-5 each pair.
// Clamps: load word base <= 4092, row <= 4095 -- corrupt only store-guarded
// outputs (proof: valid oy<=2042 needs rows<=4094, valid cols need words
// <=4094, all unclamped). 2-deep named A/B pair prefetch, unroll-1 outer.
// ---------------------------------------------------------------------------
#define CH 16     // output rows per wave strip

__global__ __launch_bounds__(256) void conv_kernel(
    const float* __restrict__ in, const float* __restrict__ kf,
    float* __restrict__ out)
{
    const int tid = threadIdx.x;
    const int wv  = tid >> 6;                   // wave -> y-strip within block
    const int l   = tid & 63;
    const int bx  = blockIdx.x;                 // 0..15  (128-col span)
    const int by  = blockIdx.y;                 // 0..31  (4 strips each)
    const int ch  = blockIdx.z;
    const int sy  = by * 4 + wv;                // strip 0..127
    const int oy0 = sy * CH;
    const int gy0 = oy0 * 2;
    const int ox0 = bx * 128;
    const int c0  = ox0 + 2 * l;                // lane's first output col
    const int Wb  = 2 * ox0 + 4 * l;            // lane's input word base

    const float* __restrict__ inc  = in  + (size_t)ch * IW * IW;
    float*       __restrict__ outc = out + (size_t)ch * OW * OW;

    // clamped load bases (words); clamp affects only invalid-output lanes
    const int w0 = (Wb      <= 4092) ? Wb      : 4092;
    const int w1 = (Wb + 4  <= 4092) ? Wb + 4  : 4092;
    const int w2 = (Wb + 8  <= 4092) ? Wb + 8  : 4092;
    const int w3 = (Wb + 12 <= 4092) ? Wb + 12 : 4092;

    float2 acc[6] = {};

    float4 Ae0, Ae1, Ae2, Ae3, Ao0, Ao1, Ao2, Ao3;
    float4 Be0, Be1, Be2, Be3, Bo0, Bo1, Bo2, Bo3;

    #define LDPAIR(T, E0,E1,E2,E3, O0,O1,O2,O3) {                             \
        int gye = gy0 + 2*(T);     if (gye > IW-1) gye = IW-1;                \
        int gyo = gy0 + 2*(T) + 1; if (gyo > IW-1) gyo = IW-1;                \
        const float* re = inc + (size_t)gye * IW;                             \
        const float* ro = inc + (size_t)gyo * IW;                             \
        E0 = *(const float4*)(re + w0);  E1 = *(const float4*)(re + w1);      \
        E2 = *(const float4*)(re + w2);  E3 = *(const float4*)(re + w3);      \
        O0 = *(const float4*)(ro + w0);  O1 = *(const float4*)(ro + w1);      \
        O2 = *(const float4*)(ro + w2);  O3 = *(const float4*)(ro + w3); }

    #define PAIRC(U, E0,E1,E2,E3, O0,O1,O2,O3) {                              \
        const float ev[16] = {E0.x,E0.y,E0.z,E0.w, E1.x,E1.y,E1.z,E1.w,       \
                              E2.x,E2.y,E2.z,E2.w, E3.x,E3.y,E3.z,E3.w};      \
        const float ov[16] = {O0.x,O0.y,O0.z,O0.w, O1.x,O1.y,O1.z,O1.w,       \
                              O2.x,O2.y,O2.z,O2.w, O3.x,O3.y,O3.z,O3.w};      \
        _Pragma("unroll")                                                     \
        for (int a = 0; a < 6; ++a) {             /* even row: ky = 2a */     \
            const int s = ((U) - a + 6) % 6;                                  \
            const float* kr = kf + (2*a) * KS;                                \
            _Pragma("unroll")                                                 \
            for (int kx = 0; kx < 11; ++kx) {                                 \
                const float w = kr[kx];                                       \
                acc[s].x = fmaf(ev[kx],     w, acc[s].x);                     \
                acc[s].y = fmaf(ev[kx + 2], w, acc[s].y);                     \
            }                                                                 \
        }                                                                     \
        _Pragma("unroll")                                                     \
        for (int a = 0; a < 5; ++a) {             /* odd row: ky = 2a+1 */    \
            const int s = ((U) - a + 6) % 6;                                  \
            const float* kr = kf + (2*a + 1) * KS;                            \
            _Pragma("unroll")                                                 \
            for (int kx = 0; kx < 11; ++kx) {                                 \
                const float w = kr[kx];                                       \
                acc[s].x = fmaf(ov[kx],     w, acc[s].x);                     \
                acc[s].y = fmaf(ov[kx + 2], w, acc[s].y);                     \
            }                                                                 \
        } }

    #define STORE(U, T) {                                                     \
        const int sc = ((U) + 1) % 6;                                         \
        if ((T) >= 5) {                                                       \
            const int oy = oy0 + (T) - 5;                                     \
            if (oy < OW) {                                                    \
                float* op = outc + (size_t)oy * OW + c0;                      \
                if (c0 < OW)     op[0] = acc[sc].x;                           \
                if (c0 + 1 < OW) op[1] = acc[sc].y;                           \
            }                                                                 \
        }                                                                     \
        acc[sc].x = 0.f; acc[sc].y = 0.f; }

    LDPAIR(0, Ae0,Ae1,Ae2,Ae3, Ao0,Ao1,Ao2,Ao3)
    int t = 0;
    #pragma unroll 1
    for (int g = 0; g < 3; ++g) {                 // pairs 0..17
        LDPAIR(t+1, Be0,Be1,Be2,Be3, Bo0,Bo1,Bo2,Bo3)
        PAIRC(0, Ae0,Ae1,Ae2,Ae3, Ao0,Ao1,Ao2,Ao3)  STORE(0, t)  ++t;
        LDPAIR(t+1, Ae0,Ae1,Ae2,Ae3, Ao0,Ao1,Ao2,Ao3)
        PAIRC(1, Be0,Be1,Be2,Be3, Bo0,Bo1,Bo2,Bo3)  STORE(1, t)  ++t;
        LDPAIR(t+1, Be0,Be1,Be2,Be3, Bo0,Bo1,Bo2,Bo3)
        PAIRC(2, Ae0,Ae1,Ae2,Ae3, Ao0,Ao1,Ao2,Ao3)  STORE(2, t)  ++t;
        LDPAIR(t+1, Ae0,Ae1,Ae2,Ae3, Ao0,Ao1,Ao2,Ao3)
        PAIRC(3, Be0,Be1,Be2,Be3, Bo0,Bo1,Bo2,Bo3)  STORE(3, t)  ++t;
        LDPAIR(t+1, Be0,Be1,Be2,Be3, Bo0,Bo1,Bo2,Bo3)
        PAIRC(4, Ae0,Ae1,Ae2,Ae3, Ao0,Ao1,Ao2,Ao3)  STORE(4, t)  ++t;
        LDPAIR(t+1, Ae0,Ae1,Ae2,Ae3, Ao0,Ao1,Ao2,Ao3)
        PAIRC(5, Be0,Be1,Be2,Be3, Bo0,Bo1,Bo2,Bo3)  STORE(5, t)  ++t;
    }
    // epilogue: pairs 18 (u=0, in A), 19 (u=1, in B), 20 (u=2, in A)
    LDPAIR(t+1, Be0,Be1,Be2,Be3, Bo0,Bo1,Bo2,Bo3)
    PAIRC(0, Ae0,Ae1,Ae2,Ae3, Ao0,Ao1,Ao2,Ao3)  STORE(0, t)  ++t;
    LDPAIR(t+1, Ae0,Ae1,Ae2,Ae3, Ao0,Ao1,Ao2,Ao3)
    PAIRC(1, Be0,Be1,Be2,Be3, Bo0,Bo1,Bo2,Bo3)  STORE(1, t)  ++t;
    PAIRC(2, Ae0,Ae1,Ae2,Ae3, Ao0,Ao1,Ao2,Ao3)  STORE(2, t)

    #undef LDPAIR
    #undef PAIRC
    #undef STORE
}

extern "C" void kernel_launch(void* const* d_in, const int* in_sizes, int n_in,
                              void* d_out, int out_size, void* d_ws, size_t ws_size,
                              hipStream_t stream)
{
    const float* in   = (const float*)d_in[0];
    const float* kc   = (const float*)d_in[1];
    const float* W1   = (const float*)d_in[2];
    const float* b1   = (const float*)d_in[3];
    const float* W2   = (const float*)d_in[4];
    const float* b2   = (const float*)d_in[5];
    const float* lg   = (const float*)d_in[6];
    const float* beta = (const float*)d_in[7];
    const float* mean = (const float*)d_in[8];
    const float* var  = (const float*)d_in[9];

    float* out  = (float*)d_out;
    float* kout = out + (size_t)3 * OW * OW;   // out_k lives at the tail of d_out

    flow_kernel<<<dim3(1), dim3(128), 0, stream>>>(kc, W1, b1, W2, b2, lg, beta, mean, var, kout);

    dim3 grid(16, 32, 3);   // 16 x-spans x 32 y-groups (4 strips each) x 3 ch
    conv_kernel<<<grid, dim3(256), 0, stream>>>(in, kout, out);
}